// Round 7
// baseline (233.235 us; speedup 1.0000x reference)
//
#include <hip/hip_runtime.h>
#include <hip/hip_bf16.h>
#include <cstddef>

#define L_ 768
#define CS_ 384
#define CZ_ 128
#define CH_ 32
#define H_ 12
#define LL_ (L_*L_)
#define EPS_ 1e-5f

typedef float f4 __attribute__((ext_vector_type(4)));

// ---------------- prep: fold LN(z) affine into w_z ----------------
__global__ void prep_kernel(const float* __restrict__ lnzw, const float* __restrict__ lnzb,
                            const float* __restrict__ wz,
                            float* __restrict__ ww, float* __restrict__ sumww,
                            float* __restrict__ bb) {
    int h = threadIdx.x;
    if (h < H_) {
        float sw = 0.f, sb = 0.f;
        for (int c = 0; c < CZ_; ++c) {
            float wv = lnzw[c] * wz[h*CZ_ + c];
            ww[h*CZ_ + c] = wv;
            sw += wv;
            sb += lnzb[c] * wz[h*CZ_ + c];
        }
        sumww[h] = sw;
        bb[h] = sb;
    }
}

// issue one 32-channel chunk: 8 x global_load_lds width16.
// ldst is wave-uniform; HW writes ldst + lane*16 (contiguous 1KB per instr).
// per instr the 64 lanes read 64 rows (stride 512B) x 16B; the 8 back-to-back
// j-instructions cover the full 128B line per row -> MSHR/L2 merges to one fetch.
__device__ __forceinline__ void bias_issue(const float* gbase, float* ldst, int c) {
    #pragma unroll
    for (int j = 0; j < 8; ++j)
        __builtin_amdgcn_global_load_lds(
            (const __attribute__((address_space(1))) unsigned int*)(gbase + c*32 + j*4),
            (__attribute__((address_space(3))) unsigned int*)(ldst + j*1024),
            16, 0, 0);
}

// ---------------- bias: fused LN(z) + pair-bias projection ----------------
// m97 pattern: double-buffered global_load_lds (no VGPR roundtrip, no ds_writes
// in main loop), 4 chunks of 32 ch, ONE barrier per chunk, issue-before-compute.
// Chunk layout [8 quads][256 rows][f4]; compute reads are contiguous-1KB b128.
__global__ __launch_bounds__(256) void bias_kernel(const float* __restrict__ z,
        const float* __restrict__ ww, const float* __restrict__ sumww,
        const float* __restrict__ bb, float* __restrict__ bias) {
    __shared__ float zbuf[2*8192];       // 64 KB: 2 bufs x [8][256][4]
    __shared__ float lw[H_*CZ_];         // 6 KB folded weights
    __shared__ float lsw[H_];
    __shared__ float lbb[H_];

    const int tid   = threadIdx.x;
    const int w     = tid >> 6;          // wave 0..3
    const int l     = tid & 63;
    const int rbase = blockIdx.x * 256;

    // per-lane global base: wave w's lanes own rows w*64 .. w*64+63
    const float* gbase = z + (size_t)(rbase + w*64 + l)*CZ_;

    for (int i = tid; i < H_*CZ_; i += 256) lw[i] = ww[i];
    if (tid < H_) { lsw[tid] = sumww[tid]; lbb[tid] = bb[tid]; }

    float acc[H_];
    #pragma unroll
    for (int h = 0; h < H_; ++h) acc[h] = 0.f;
    float sum = 0.f, sum2 = 0.f;

    bias_issue(gbase, zbuf + w*256, 0);  // chunk 0 -> buf 0
    __syncthreads();                     // vmcnt(0): chunk0 landed; lw ready

    int cur = 0;
    #pragma unroll 1
    for (int c0 = 0; c0 < 4; ++c0) {
        if (c0 < 3)
            bias_issue(gbase, zbuf + (cur^1)*8192 + w*256, c0+1);
        // compute chunk c0 from buf cur: my row = tid
        #pragma unroll
        for (int j = 0; j < 8; ++j) {
            f4 zv = *(const f4*)&zbuf[cur*8192 + j*1024 + tid*4];
            const int cbase = c0*32 + j*4;
            sum  += zv.x + zv.y + zv.z + zv.w;
            sum2 += zv.x*zv.x + zv.y*zv.y + zv.z*zv.z + zv.w*zv.w;
            #pragma unroll
            for (int h = 0; h < H_; ++h) {
                f4 wv = *(const f4*)&lw[h*CZ_ + cbase];   // uniform addr -> broadcast
                acc[h] += zv.x*wv.x + zv.y*wv.y + zv.z*wv.z + zv.w*wv.w;
            }
        }
        __syncthreads();                 // drains vmcnt: next buf ready
        cur ^= 1;
    }

    // ---- epilogue: LN, transpose through LDS (reuse zbuf), f4 coalesced stores ----
    float m = sum * (1.f/CZ_);
    float r = rsqrtf(sum2*(1.f/CZ_) - m*m + EPS_);
    #pragma unroll
    for (int h = 0; h < H_; ++h)
        zbuf[tid*17 + h] = r*(acc[h] - m*lsw[h]) + lbb[h];
    __syncthreads();
    #pragma unroll
    for (int it = 0; it < 3; ++it) {
        int idx = it*256 + tid;
        int h   = idx >> 6;              // wave-uniform head per instruction
        int qd  = idx & 63;
        f4 o;
        o.x = zbuf[(qd*4 + 0)*17 + h];
        o.y = zbuf[(qd*4 + 1)*17 + h];
        o.z = zbuf[(qd*4 + 2)*17 + h];
        o.w = zbuf[(qd*4 + 3)*17 + h];
        *(f4*)(bias + (size_t)h*LL_ + rbase + qd*4) = o;   // 1KB contiguous / wave instr
    }
}

// ---------------- LayerNorm(s) ----------------
__global__ void sln_kernel(const float* __restrict__ s, const float* __restrict__ w,
                           const float* __restrict__ b, float* __restrict__ sn) {
    int row = blockIdx.x;
    int lane = threadIdx.x;   // 64
    float x[6];
    float sum = 0.f, sum2 = 0.f;
    #pragma unroll
    for (int j = 0; j < 6; ++j) {
        x[j] = s[row*CS_ + lane + j*64];
        sum += x[j]; sum2 += x[j]*x[j];
    }
    #pragma unroll
    for (int off = 32; off; off >>= 1) {
        sum  += __shfl_xor(sum,  off);
        sum2 += __shfl_xor(sum2, off);
    }
    float m = sum * (1.f/CS_);
    float r = rsqrtf(sum2*(1.f/CS_) - m*m + EPS_);
    #pragma unroll
    for (int j = 0; j < 6; ++j) {
        int c = lane + j*64;
        sn[row*CS_ + c] = (x[j]-m)*r*w[c] + b[c];
    }
}

// ---------------- QKVG projections ----------------
__global__ __launch_bounds__(256) void qkvg_kernel(const float* __restrict__ sn,
        const float* __restrict__ wq, const float* __restrict__ wk,
        const float* __restrict__ wv, const float* __restrict__ wg,
        const float* __restrict__ bg,
        float* __restrict__ qb, float* __restrict__ kb,
        float* __restrict__ vb, float* __restrict__ gb) {
    __shared__ float As[16][68];
    __shared__ float Bs[16][68];
    int m0 = blockIdx.x * 64;
    int n0 = blockIdx.y * 64;
    int sel = n0 / 384;
    const float* W = (sel==0) ? wq : (sel==1) ? wk : (sel==2) ? wv : wg;
    float* C       = (sel==0) ? qb : (sel==1) ? kb : (sel==2) ? vb : gb;
    int ncol0 = n0 - sel*384;

    int t  = threadIdx.x;
    int lr = t >> 2;
    int lc = (t & 3) * 4;
    int ty = t >> 4;
    int tx = t & 15;

    float acc[4][4] = {};
    for (int k0 = 0; k0 < CS_; k0 += 16) {
        float4 av = *(const float4*)(sn + (size_t)(m0 + lr)*CS_ + k0 + lc);
        float4 bv = *(const float4*)(W  + (size_t)(ncol0 + lr)*CS_ + k0 + lc);
        As[lc+0][lr] = av.x; As[lc+1][lr] = av.y; As[lc+2][lr] = av.z; As[lc+3][lr] = av.w;
        Bs[lc+0][lr] = bv.x; Bs[lc+1][lr] = bv.y; Bs[lc+2][lr] = bv.z; Bs[lc+3][lr] = bv.w;
        __syncthreads();
        #pragma unroll
        for (int kk = 0; kk < 16; ++kk) {
            float4 a4 = *(const float4*)&As[kk][ty*4];
            float4 b4 = *(const float4*)&Bs[kk][tx*4];
            float a[4] = {a4.x,a4.y,a4.z,a4.w};
            float bb_[4] = {b4.x,b4.y,b4.z,b4.w};
            #pragma unroll
            for (int i = 0; i < 4; ++i)
                #pragma unroll
                for (int j = 0; j < 4; ++j)
                    acc[i][j] += a[i]*bb_[j];
        }
        __syncthreads();
    }
    #pragma unroll
    for (int i = 0; i < 4; ++i) {
        int row = m0 + ty*4 + i;
        #pragma unroll
        for (int j = 0; j < 4; ++j) {
            int col = ncol0 + tx*4 + j;
            float v = acc[i][j];
            if (sel == 0) v *= 0.17677669529663687f;
            if (sel == 3) v = 1.f/(1.f + __expf(-(v + bg[col])));
            C[(size_t)row*CS_ + col] = v;
        }
    }
}

// ---------------- attention: QT=8 rows/block, KT=128 tiles ----------------
// grid (12, 96) = 1152 blocks (vs 144 before: GPU was 44% idle).
#define QT_ 8
__global__ __launch_bounds__(256) void attn_kernel(const float* __restrict__ qb,
        const float* __restrict__ kb, const float* __restrict__ vb,
        const float* __restrict__ gb, const float* __restrict__ bias,
        float* __restrict__ og) {
    __shared__ float Sm[QT_][772];       // 24.7 KB scores
    __shared__ float KVt[CH_][136];      // 17.4 KB K or V tile transposed [c][k]
    int h  = blockIdx.x;
    int q0 = blockIdx.y * QT_;
    int t  = threadIdx.x;

    int tq = t >> 5;    // 0..7 q row
    int tk = t & 31;    // 0..31 k-quad / channel

    float qreg[CH_];
    {
        const float4* qsrc = (const float4*)(qb + (size_t)(q0 + tq)*CS_ + h*CH_);
        #pragma unroll
        for (int i = 0; i < 8; ++i) {
            float4 qv = qsrc[i];
            qreg[i*4+0]=qv.x; qreg[i*4+1]=qv.y; qreg[i*4+2]=qv.z; qreg[i*4+3]=qv.w;
        }
    }

    // ---- phase 1: S = qK^T + bias ----
    for (int kt = 0; kt < L_; kt += 128) {
        #pragma unroll
        for (int r2 = 0; r2 < 4; ++r2) {
            int row = (t >> 3) + 32*r2;        // 0..127
            int c   = (t & 7) * 4;
            f4 kv = *(const f4*)(kb + (size_t)(kt+row)*CS_ + h*CH_ + c);
            KVt[c+0][row]=kv.x; KVt[c+1][row]=kv.y; KVt[c+2][row]=kv.z; KVt[c+3][row]=kv.w;
        }
        __syncthreads();
        f4 sacc = {0,0,0,0};
        #pragma unroll
        for (int c = 0; c < CH_; ++c) {
            f4 kv4 = *(const f4*)&KVt[c][tk*4];
            sacc.x += qreg[c]*kv4.x;
            sacc.y += qreg[c]*kv4.y;
            sacc.z += qreg[c]*kv4.z;
            sacc.w += qreg[c]*kv4.w;
        }
        f4 bv = *(const f4*)(bias + (size_t)h*LL_ + (size_t)(q0+tq)*L_ + kt + tk*4);
        *(f4*)&Sm[tq][kt + tk*4] = sacc + bv;
        __syncthreads();
    }

    // ---- phase 2: softmax (32 lanes per row) ----
    {
        float mx = -1e30f;
        for (int k = tk; k < L_; k += 32) mx = fmaxf(mx, Sm[tq][k]);
        #pragma unroll
        for (int off = 16; off; off >>= 1) mx = fmaxf(mx, __shfl_xor(mx, off));
        float ssum = 0.f;
        for (int k = tk; k < L_; k += 32) {
            float e = __expf(Sm[tq][k] - mx);
            Sm[tq][k] = e;
            ssum += e;
        }
        #pragma unroll
        for (int off = 16; off; off >>= 1) ssum += __shfl_xor(ssum, off);
        float inv = 1.f/ssum;
        for (int k = tk; k < L_; k += 32) Sm[tq][k] *= inv;
        __syncthreads();
    }

    // ---- phase 3: O = P V, gated store (1 channel per thread) ----
    {
        float o = 0.f;
        for (int kt = 0; kt < L_; kt += 128) {
            #pragma unroll
            for (int r2 = 0; r2 < 4; ++r2) {
                int row = (t >> 3) + 32*r2;
                int c   = (t & 7) * 4;
                f4 vv = *(const f4*)(vb + (size_t)(kt+row)*CS_ + h*CH_ + c);
                KVt[c+0][row]=vv.x; KVt[c+1][row]=vv.y; KVt[c+2][row]=vv.z; KVt[c+3][row]=vv.w;
            }
            __syncthreads();
            #pragma unroll
            for (int j4 = 0; j4 < 32; ++j4) {
                f4 pv = *(const f4*)&Sm[tq][kt + j4*4];
                f4 va = *(const f4*)&KVt[tk][j4*4];
                o += pv.x*va.x + pv.y*va.y + pv.z*va.z + pv.w*va.w;
            }
            __syncthreads();
        }
        int row = q0 + tq;
        int c   = h*CH_ + tk;
        og[(size_t)row*CS_ + c] = o * gb[(size_t)row*CS_ + c];
    }
}

// ---------------- out projection ----------------
__global__ __launch_bounds__(256) void outproj_kernel(const float* __restrict__ og,
        const float* __restrict__ wo, const float* __restrict__ bo,
        float* __restrict__ out) {
    __shared__ float As[16][68];
    __shared__ float Bs[16][68];
    int m0 = blockIdx.x * 64;
    int n0 = blockIdx.y * 64;
    int t  = threadIdx.x;
    int lr = t >> 2;
    int lc = (t & 3) * 4;
    int ty = t >> 4;
    int tx = t & 15;
    float acc[4][4] = {};
    for (int k0 = 0; k0 < CS_; k0 += 16) {
        float4 av = *(const float4*)(og + (size_t)(m0 + lr)*CS_ + k0 + lc);
        float4 bv = *(const float4*)(wo + (size_t)(n0 + lr)*CS_ + k0 + lc);
        As[lc+0][lr] = av.x; As[lc+1][lr] = av.y; As[lc+2][lr] = av.z; As[lc+3][lr] = av.w;
        Bs[lc+0][lr] = bv.x; Bs[lc+1][lr] = bv.y; Bs[lc+2][lr] = bv.z; Bs[lc+3][lr] = bv.w;
        __syncthreads();
        #pragma unroll
        for (int kk = 0; kk < 16; ++kk) {
            float4 a4 = *(const float4*)&As[kk][ty*4];
            float4 b4 = *(const float4*)&Bs[kk][tx*4];
            float a[4] = {a4.x,a4.y,a4.z,a4.w};
            float bb_[4] = {b4.x,b4.y,b4.z,b4.w};
            #pragma unroll
            for (int i = 0; i < 4; ++i)
                #pragma unroll
                for (int j = 0; j < 4; ++j)
                    acc[i][j] += a[i]*bb_[j];
        }
        __syncthreads();
    }
    #pragma unroll
    for (int i = 0; i < 4; ++i) {
        int row = m0 + ty*4 + i;
        #pragma unroll
        for (int j = 0; j < 4; ++j) {
            int col = n0 + tx*4 + j;
            out[(size_t)row*CS_ + col] = acc[i][j] + bo[col];
        }
    }
}

extern "C" void kernel_launch(void* const* d_in, const int* in_sizes, int n_in,
                              void* d_out, int out_size, void* d_ws, size_t ws_size,
                              hipStream_t stream) {
    const float* s      = (const float*)d_in[0];
    const float* z      = (const float*)d_in[1];
    const float* ln_s_w = (const float*)d_in[2];
    const float* ln_s_b = (const float*)d_in[3];
    const float* ln_z_w = (const float*)d_in[4];
    const float* ln_z_b = (const float*)d_in[5];
    const float* w_z    = (const float*)d_in[6];
    const float* w_q    = (const float*)d_in[7];
    const float* w_k    = (const float*)d_in[8];
    const float* w_v    = (const float*)d_in[9];
    const float* w_g    = (const float*)d_in[10];
    const float* b_g    = (const float*)d_in[11];
    const float* w_o    = (const float*)d_in[12];
    const float* b_o    = (const float*)d_in[13];
    float* out = (float*)d_out;

    float* ws    = (float*)d_ws;
    float* bias  = ws;
    float* sn    = bias + (size_t)H_*LL_;
    float* qb    = sn + (size_t)L_*CS_;
    float* kb    = qb + (size_t)L_*CS_;
    float* vb    = kb + (size_t)L_*CS_;
    float* gb    = vb + (size_t)L_*CS_;
    float* og    = gb + (size_t)L_*CS_;
    float* ww    = og + (size_t)L_*CS_;
    float* sumww = ww + (size_t)H_*CZ_;
    float* bbuf  = sumww + 16;

    hipLaunchKernelGGL(prep_kernel, dim3(1), dim3(64), 0, stream,
                       ln_z_w, ln_z_b, w_z, ww, sumww, bbuf);
    hipLaunchKernelGGL(bias_kernel, dim3(LL_/256), dim3(256), 0, stream,
                       z, ww, sumww, bbuf, bias);
    hipLaunchKernelGGL(sln_kernel, dim3(L_), dim3(64), 0, stream,
                       s, ln_s_w, ln_s_b, sn);
    hipLaunchKernelGGL(qkvg_kernel, dim3(L_/64, 1536/64), dim3(256), 0, stream,
                       sn, w_q, w_k, w_v, w_g, b_g, qb, kb, vb, gb);
    hipLaunchKernelGGL(attn_kernel, dim3(H_, L_/QT_), dim3(256), 0, stream,
                       qb, kb, vb, gb, bias, og);
    hipLaunchKernelGGL(outproj_kernel, dim3(L_/64, CS_/64), dim3(256), 0, stream,
                       og, w_o, b_o, out);
}

// Round 8
// 209.903 us; speedup vs baseline: 1.1112x; 1.1112x over previous
//
#include <hip/hip_runtime.h>
#include <hip/hip_bf16.h>
#include <cstddef>

#define L_ 768
#define CS_ 384
#define CZ_ 128
#define CH_ 32
#define H_ 12
#define LL_ (L_*L_)
#define EPS_ 1e-5f

typedef float f4 __attribute__((ext_vector_type(4)));

// ---------------- prep: fold LN(z) affine into w_z ----------------
__global__ void prep_kernel(const float* __restrict__ lnzw, const float* __restrict__ lnzb,
                            const float* __restrict__ wz,
                            float* __restrict__ ww, float* __restrict__ sumww,
                            float* __restrict__ bb) {
    int h = threadIdx.x;
    if (h < H_) {
        float sw = 0.f, sb = 0.f;
        for (int c = 0; c < CZ_; ++c) {
            float wv = lnzw[c] * wz[h*CZ_ + c];
            ww[h*CZ_ + c] = wv;
            sw += wv;
            sb += lnzb[c] * wz[h*CZ_ + c];
        }
        sumww[h] = sw;
        bb[h] = sb;
    }
}

// ---------------- bias: register-tiled [256rows x 128] @ [128 x 12] + fused LN ----
// 128 threads, 2 rows/thread (halves the fixed per-wave uniform weight-read cost
// that made R4-R7 DS-pipe-bound). Chunk = 32 ch = full 128B line:
// stage instr = 8 rows x full line (100% utilization, no line-reuse bet).
// Dbuf alternation -> ONE barrier per chunk; next chunk's loads fly during
// compute (T14). Banks: write quad (sr+s8)%8, read quad (t+j)%8 -> b128 minimum.
__global__ __launch_bounds__(128) void bias_kernel(const float* __restrict__ z,
        const float* __restrict__ ww, const float* __restrict__ sumww,
        const float* __restrict__ bb, float* __restrict__ bias) {
    __shared__ float zb[2][256][36];     // 72 KB: 2 bufs x 256 rows x (32ch + pad)
    __shared__ float lw[H_*CZ_];         // 6 KB folded weights
    __shared__ float lsw[H_];
    __shared__ float lbb[H_];

    const int t  = threadIdx.x;          // 0..127
    const size_t tb = (size_t)blockIdx.x * 256;  // tile row base
    const int sr = t >> 3;               // 0..15 staging row group
    const int s8 = t & 7;                // 0..7  16B slot in line

    const f4* zf4 = (const f4*)z;        // z as f4[589824*32]

    // issue chunk 0 loads first (hide latency under weight staging)
    f4 st[16];
    #pragma unroll
    for (int p = 0; p < 16; ++p)
        st[p] = __builtin_nontemporal_load(&zf4[(tb + p*16 + sr)*32 + s8]);

    {   // weights -> LDS (1536 floats = 384 f4; 3 per thread)
        const f4* wwf4 = (const f4*)ww;
        f4* lwf4 = (f4*)lw;
        #pragma unroll
        for (int i = 0; i < 3; ++i) lwf4[i*128 + t] = wwf4[i*128 + t];
        if (t < H_) { lsw[t] = sumww[t]; lbb[t] = bb[t]; }
    }

    float acc0[H_], acc1[H_];
    #pragma unroll
    for (int h = 0; h < H_; ++h) { acc0[h] = 0.f; acc1[h] = 0.f; }
    float s0 = 0.f, q0 = 0.f, s1 = 0.f, q1 = 0.f;

    #pragma unroll 1
    for (int c = 0; c < 4; ++c) {
        // write chunk c (st) -> buf c&1. Prior readers of this buf finished
        // 2 chunks ago, ordered by the intervening barrier -> no barrier here.
        #pragma unroll
        for (int p = 0; p < 16; ++p)
            *(f4*)&zb[c&1][p*16 + sr][s8*4] = st[p];
        if (c < 3) {
            #pragma unroll
            for (int p = 0; p < 16; ++p)    // chunk c+1 in flight during compute c
                st[p] = __builtin_nontemporal_load(&zf4[(tb + p*16 + sr)*32 + (c+1)*8 + s8]);
        }
        __syncthreads();                 // buf c&1 ready (and lw ready at c==0)

        #pragma unroll
        for (int j = 0; j < 8; ++j) {
            f4 z0 = *(const f4*)&zb[c&1][t][j*4];
            f4 z1 = *(const f4*)&zb[c&1][t+128][j*4];
            s0 += z0.x+z0.y+z0.z+z0.w;
            q0 += z0.x*z0.x+z0.y*z0.y+z0.z*z0.z+z0.w*z0.w;
            s1 += z1.x+z1.y+z1.z+z1.w;
            q1 += z1.x*z1.x+z1.y*z1.y+z1.z*z1.z+z1.w*z1.w;
            const int cb = c*32 + j*4;
            #pragma unroll
            for (int h = 0; h < H_; ++h) {
                f4 wv = *(const f4*)&lw[h*CZ_ + cb];   // uniform -> broadcast, serves 2 rows
                acc0[h] += z0.x*wv.x + z0.y*wv.y + z0.z*wv.z + z0.w*wv.w;
                acc1[h] += z1.x*wv.x + z1.y*wv.y + z1.z*wv.z + z1.w*wv.w;
            }
        }
        __syncthreads();                 // all reads of buf c&1 done
    }

    // ---- epilogue: LN + coalesced stores (256B per wave instr per head) ----
    float m0 = s0 * (1.f/CZ_);
    float r0 = rsqrtf(q0*(1.f/CZ_) - m0*m0 + EPS_);
    float m1 = s1 * (1.f/CZ_);
    float r1 = rsqrtf(q1*(1.f/CZ_) - m1*m1 + EPS_);
    #pragma unroll
    for (int h = 0; h < H_; ++h) {
        bias[(size_t)h*LL_ + tb + t]       = r0*(acc0[h] - m0*lsw[h]) + lbb[h];
        bias[(size_t)h*LL_ + tb + 128 + t] = r1*(acc1[h] - m1*lsw[h]) + lbb[h];
    }
}

// ---------------- LayerNorm(s) ----------------
__global__ void sln_kernel(const float* __restrict__ s, const float* __restrict__ w,
                           const float* __restrict__ b, float* __restrict__ sn) {
    int row = blockIdx.x;
    int lane = threadIdx.x;   // 64
    float x[6];
    float sum = 0.f, sum2 = 0.f;
    #pragma unroll
    for (int j = 0; j < 6; ++j) {
        x[j] = s[row*CS_ + lane + j*64];
        sum += x[j]; sum2 += x[j]*x[j];
    }
    #pragma unroll
    for (int off = 32; off; off >>= 1) {
        sum  += __shfl_xor(sum,  off);
        sum2 += __shfl_xor(sum2, off);
    }
    float m = sum * (1.f/CS_);
    float r = rsqrtf(sum2*(1.f/CS_) - m*m + EPS_);
    #pragma unroll
    for (int j = 0; j < 6; ++j) {
        int c = lane + j*64;
        sn[row*CS_ + c] = (x[j]-m)*r*w[c] + b[c];
    }
}

// ---------------- QKVG projections ----------------
__global__ __launch_bounds__(256) void qkvg_kernel(const float* __restrict__ sn,
        const float* __restrict__ wq, const float* __restrict__ wk,
        const float* __restrict__ wv, const float* __restrict__ wg,
        const float* __restrict__ bg,
        float* __restrict__ qb, float* __restrict__ kb,
        float* __restrict__ vb, float* __restrict__ gb) {
    __shared__ float As[16][68];
    __shared__ float Bs[16][68];
    int m0 = blockIdx.x * 64;
    int n0 = blockIdx.y * 64;
    int sel = n0 / 384;
    const float* W = (sel==0) ? wq : (sel==1) ? wk : (sel==2) ? wv : wg;
    float* C       = (sel==0) ? qb : (sel==1) ? kb : (sel==2) ? vb : gb;
    int ncol0 = n0 - sel*384;

    int t  = threadIdx.x;
    int lr = t >> 2;
    int lc = (t & 3) * 4;
    int ty = t >> 4;
    int tx = t & 15;

    float acc[4][4] = {};
    for (int k0 = 0; k0 < CS_; k0 += 16) {
        float4 av = *(const float4*)(sn + (size_t)(m0 + lr)*CS_ + k0 + lc);
        float4 bv = *(const float4*)(W  + (size_t)(ncol0 + lr)*CS_ + k0 + lc);
        As[lc+0][lr] = av.x; As[lc+1][lr] = av.y; As[lc+2][lr] = av.z; As[lc+3][lr] = av.w;
        Bs[lc+0][lr] = bv.x; Bs[lc+1][lr] = bv.y; Bs[lc+2][lr] = bv.z; Bs[lc+3][lr] = bv.w;
        __syncthreads();
        #pragma unroll
        for (int kk = 0; kk < 16; ++kk) {
            float4 a4 = *(const float4*)&As[kk][ty*4];
            float4 b4 = *(const float4*)&Bs[kk][tx*4];
            float a[4] = {a4.x,a4.y,a4.z,a4.w};
            float bb_[4] = {b4.x,b4.y,b4.z,b4.w};
            #pragma unroll
            for (int i = 0; i < 4; ++i)
                #pragma unroll
                for (int j = 0; j < 4; ++j)
                    acc[i][j] += a[i]*bb_[j];
        }
        __syncthreads();
    }
    #pragma unroll
    for (int i = 0; i < 4; ++i) {
        int row = m0 + ty*4 + i;
        #pragma unroll
        for (int j = 0; j < 4; ++j) {
            int col = ncol0 + tx*4 + j;
            float v = acc[i][j];
            if (sel == 0) v *= 0.17677669529663687f;
            if (sel == 3) v = 1.f/(1.f + __expf(-(v + bg[col])));
            C[(size_t)row*CS_ + col] = v;
        }
    }
}

// ---------------- attention: QT=8 rows/block, KT=128 tiles ----------------
#define QT_ 8
__global__ __launch_bounds__(256) void attn_kernel(const float* __restrict__ qb,
        const float* __restrict__ kb, const float* __restrict__ vb,
        const float* __restrict__ gb, const float* __restrict__ bias,
        float* __restrict__ og) {
    __shared__ float Sm[QT_][772];       // 24.7 KB scores
    __shared__ float KVt[CH_][136];      // 17.4 KB K or V tile transposed [c][k]
    int h  = blockIdx.x;
    int q0 = blockIdx.y * QT_;
    int t  = threadIdx.x;

    int tq = t >> 5;    // 0..7 q row
    int tk = t & 31;    // 0..31 k-quad / channel

    float qreg[CH_];
    {
        const float4* qsrc = (const float4*)(qb + (size_t)(q0 + tq)*CS_ + h*CH_);
        #pragma unroll
        for (int i = 0; i < 8; ++i) {
            float4 qv = qsrc[i];
            qreg[i*4+0]=qv.x; qreg[i*4+1]=qv.y; qreg[i*4+2]=qv.z; qreg[i*4+3]=qv.w;
        }
    }

    // ---- phase 1: S = qK^T + bias ----
    for (int kt = 0; kt < L_; kt += 128) {
        #pragma unroll
        for (int r2 = 0; r2 < 4; ++r2) {
            int row = (t >> 3) + 32*r2;        // 0..127
            int c   = (t & 7) * 4;
            f4 kv = *(const f4*)(kb + (size_t)(kt+row)*CS_ + h*CH_ + c);
            KVt[c+0][row]=kv.x; KVt[c+1][row]=kv.y; KVt[c+2][row]=kv.z; KVt[c+3][row]=kv.w;
        }
        __syncthreads();
        f4 sacc = {0,0,0,0};
        #pragma unroll
        for (int c = 0; c < CH_; ++c) {
            f4 kv4 = *(const f4*)&KVt[c][tk*4];
            sacc.x += qreg[c]*kv4.x;
            sacc.y += qreg[c]*kv4.y;
            sacc.z += qreg[c]*kv4.z;
            sacc.w += qreg[c]*kv4.w;
        }
        f4 bv = *(const f4*)(bias + (size_t)h*LL_ + (size_t)(q0+tq)*L_ + kt + tk*4);
        *(f4*)&Sm[tq][kt + tk*4] = sacc + bv;
        __syncthreads();
    }

    // ---- phase 2: softmax (32 lanes per row) ----
    {
        float mx = -1e30f;
        for (int k = tk; k < L_; k += 32) mx = fmaxf(mx, Sm[tq][k]);
        #pragma unroll
        for (int off = 16; off; off >>= 1) mx = fmaxf(mx, __shfl_xor(mx, off));
        float ssum = 0.f;
        for (int k = tk; k < L_; k += 32) {
            float e = __expf(Sm[tq][k] - mx);
            Sm[tq][k] = e;
            ssum += e;
        }
        #pragma unroll
        for (int off = 16; off; off >>= 1) ssum += __shfl_xor(ssum, off);
        float inv = 1.f/ssum;
        for (int k = tk; k < L_; k += 32) Sm[tq][k] *= inv;
        __syncthreads();
    }

    // ---- phase 3: O = P V, gated store (1 channel per thread) ----
    {
        float o = 0.f;
        for (int kt = 0; kt < L_; kt += 128) {
            #pragma unroll
            for (int r2 = 0; r2 < 4; ++r2) {
                int row = (t >> 3) + 32*r2;
                int c   = (t & 7) * 4;
                f4 vv = *(const f4*)(vb + (size_t)(kt+row)*CS_ + h*CH_ + c);
                KVt[c+0][row]=vv.x; KVt[c+1][row]=vv.y; KVt[c+2][row]=vv.z; KVt[c+3][row]=vv.w;
            }
            __syncthreads();
            #pragma unroll
            for (int j4 = 0; j4 < 32; ++j4) {
                f4 pv = *(const f4*)&Sm[tq][kt + j4*4];
                f4 va = *(const f4*)&KVt[tk][j4*4];
                o += pv.x*va.x + pv.y*va.y + pv.z*va.z + pv.w*va.w;
            }
            __syncthreads();
        }
        int row = q0 + tq;
        int c   = h*CH_ + tk;
        og[(size_t)row*CS_ + c] = o * gb[(size_t)row*CS_ + c];
    }
}

// ---------------- out projection ----------------
__global__ __launch_bounds__(256) void outproj_kernel(const float* __restrict__ og,
        const float* __restrict__ wo, const float* __restrict__ bo,
        float* __restrict__ out) {
    __shared__ float As[16][68];
    __shared__ float Bs[16][68];
    int m0 = blockIdx.x * 64;
    int n0 = blockIdx.y * 64;
    int t  = threadIdx.x;
    int lr = t >> 2;
    int lc = (t & 3) * 4;
    int ty = t >> 4;
    int tx = t & 15;
    float acc[4][4] = {};
    for (int k0 = 0; k0 < CS_; k0 += 16) {
        float4 av = *(const float4*)(og + (size_t)(m0 + lr)*CS_ + k0 + lc);
        float4 bv = *(const float4*)(wo + (size_t)(n0 + lr)*CS_ + k0 + lc);
        As[lc+0][lr] = av.x; As[lc+1][lr] = av.y; As[lc+2][lr] = av.z; As[lc+3][lr] = av.w;
        Bs[lc+0][lr] = bv.x; Bs[lc+1][lr] = bv.y; Bs[lc+2][lr] = bv.z; Bs[lc+3][lr] = bv.w;
        __syncthreads();
        #pragma unroll
        for (int kk = 0; kk < 16; ++kk) {
            float4 a4 = *(const float4*)&As[kk][ty*4];
            float4 b4 = *(const float4*)&Bs[kk][tx*4];
            float a[4] = {a4.x,a4.y,a4.z,a4.w};
            float bb_[4] = {b4.x,b4.y,b4.z,b4.w};
            #pragma unroll
            for (int i = 0; i < 4; ++i)
                #pragma unroll
                for (int j = 0; j < 4; ++j)
                    acc[i][j] += a[i]*bb_[j];
        }
        __syncthreads();
    }
    #pragma unroll
    for (int i = 0; i < 4; ++i) {
        int row = m0 + ty*4 + i;
        #pragma unroll
        for (int j = 0; j < 4; ++j) {
            int col = n0 + tx*4 + j;
            out[(size_t)row*CS_ + col] = acc[i][j] + bo[col];
        }
    }
}

extern "C" void kernel_launch(void* const* d_in, const int* in_sizes, int n_in,
                              void* d_out, int out_size, void* d_ws, size_t ws_size,
                              hipStream_t stream) {
    const float* s      = (const float*)d_in[0];
    const float* z      = (const float*)d_in[1];
    const float* ln_s_w = (const float*)d_in[2];
    const float* ln_s_b = (const float*)d_in[3];
    const float* ln_z_w = (const float*)d_in[4];
    const float* ln_z_b = (const float*)d_in[5];
    const float* w_z    = (const float*)d_in[6];
    const float* w_q    = (const float*)d_in[7];
    const float* w_k    = (const float*)d_in[8];
    const float* w_v    = (const float*)d_in[9];
    const float* w_g    = (const float*)d_in[10];
    const float* b_g    = (const float*)d_in[11];
    const float* w_o    = (const float*)d_in[12];
    const float* b_o    = (const float*)d_in[13];
    float* out = (float*)d_out;

    float* ws    = (float*)d_ws;
    float* bias  = ws;
    float* sn    = bias + (size_t)H_*LL_;
    float* qb    = sn + (size_t)L_*CS_;
    float* kb    = qb + (size_t)L_*CS_;
    float* vb    = kb + (size_t)L_*CS_;
    float* gb    = vb + (size_t)L_*CS_;
    float* og    = gb + (size_t)L_*CS_;
    float* ww    = og + (size_t)L_*CS_;
    float* sumww = ww + (size_t)H_*CZ_;
    float* bbuf  = sumww + 16;

    hipLaunchKernelGGL(prep_kernel, dim3(1), dim3(64), 0, stream,
                       ln_z_w, ln_z_b, w_z, ww, sumww, bbuf);
    hipLaunchKernelGGL(bias_kernel, dim3(LL_/256), dim3(128), 0, stream,
                       z, ww, sumww, bbuf, bias);
    hipLaunchKernelGGL(sln_kernel, dim3(L_), dim3(64), 0, stream,
                       s, ln_s_w, ln_s_b, sn);
    hipLaunchKernelGGL(qkvg_kernel, dim3(L_/64, 1536/64), dim3(256), 0, stream,
                       sn, w_q, w_k, w_v, w_g, b_g, qb, kb, vb, gb);
    hipLaunchKernelGGL(attn_kernel, dim3(H_, L_/QT_), dim3(256), 0, stream,
                       qb, kb, vb, gb, bias, og);
    hipLaunchKernelGGL(outproj_kernel, dim3(L_/64, CS_/64), dim3(256), 0, stream,
                       og, w_o, b_o, out);
}

// Round 9
// 209.122 us; speedup vs baseline: 1.1153x; 1.0037x over previous
//
#include <hip/hip_runtime.h>
#include <hip/hip_bf16.h>
#include <cstddef>

#define L_ 768
#define CS_ 384
#define CZ_ 128
#define CH_ 32
#define H_ 12
#define LL_ (L_*L_)
#define EPS_ 1e-5f

typedef float f4 __attribute__((ext_vector_type(4)));
typedef float f2 __attribute__((ext_vector_type(2)));

// ---------------- prep: fold LN(z) affine into w_z ----------------
__global__ void prep_kernel(const float* __restrict__ lnzw, const float* __restrict__ lnzb,
                            const float* __restrict__ wz,
                            float* __restrict__ ww, float* __restrict__ sumww,
                            float* __restrict__ bb) {
    int h = threadIdx.x;
    if (h < H_) {
        float sw = 0.f, sb = 0.f;
        for (int c = 0; c < CZ_; ++c) {
            float wv = lnzw[c] * wz[h*CZ_ + c];
            ww[h*CZ_ + c] = wv;
            sw += wv;
            sb += lnzb[c] * wz[h*CZ_ + c];
        }
        sumww[h] = sw;
        bb[h] = sb;
    }
}

// ---------------- bias: register-tiled, R=4 rows x Hh=6 heads per thread ----
// DS ledger per block per chunk: 384*(1/R + 1/Hh) = 160 wave-instr (R8 was 224)
// -> 4.6K cy/CU/chunk vs HBM 6.4K: DS now strictly under HBM.
// 128 threads: wave0 = heads 0-5, wave1 = heads 6-11 (weight reads wave-uniform).
// rg = t&63 owns rows rg*4..rg*4+3 -> epilogue is direct coalesced f4 stores.
// z-read banks: quad (36rg*4+36i+4j)/4 mod 32 -> 8 quads x 8 lanes = b128 minimum.
__global__ __launch_bounds__(128) void bias_kernel(const float* __restrict__ z,
        const float* __restrict__ ww, const float* __restrict__ sumww,
        const float* __restrict__ bb, float* __restrict__ bias) {
    __shared__ float zb[2][256*36];      // 72 KB: 2 bufs x 256 rows x (32ch+pad)
    __shared__ float lw[H_*CZ_];         // 6 KB folded weights
    __shared__ float lsw[H_];
    __shared__ float lbb[H_];

    const int t  = threadIdx.x;          // 0..127
    const size_t tb = (size_t)blockIdx.x * 256;
    const int sr = t >> 3;               // staging: row group 0..15
    const int s8 = t & 7;                // staging: 16B slot in 128B line
    const int rg = t & 63;               // compute: row quad 0..63
    const int hg = t >> 6;               // compute: head group 0..1 (== wave id)

    const f4* zf4 = (const f4*)z;

    // issue chunk 0 (16 x coalesced full-line loads: 8 rows x 128B per wave instr)
    f4 st[16];
    #pragma unroll
    for (int p = 0; p < 16; ++p)
        st[p] = __builtin_nontemporal_load(&zf4[(tb + p*16 + sr)*32 + s8]);

    {   // weights -> LDS
        const f4* wwf4 = (const f4*)ww;
        f4* lwf4 = (f4*)lw;
        #pragma unroll
        for (int i = 0; i < 3; ++i) lwf4[i*128 + t] = wwf4[i*128 + t];
        if (t < H_) { lsw[t] = sumww[t]; lbb[t] = bb[t]; }
    }

    float acc[6][4];
    #pragma unroll
    for (int h = 0; h < 6; ++h)
        #pragma unroll
        for (int i = 0; i < 4; ++i) acc[h][i] = 0.f;
    float sm[4] = {0,0,0,0}, sq[4] = {0,0,0,0};

    #pragma unroll 1
    for (int c = 0; c < 4; ++c) {
        // write chunk c -> buf c&1 (readers of this buf finished 2 chunks ago,
        // ordered by the intervening barriers)
        #pragma unroll
        for (int p = 0; p < 16; ++p)
            *(f4*)&zb[c&1][(p*16 + sr)*36 + s8*4] = st[p];
        if (c < 3) {
            #pragma unroll
            for (int p = 0; p < 16; ++p)    // chunk c+1 in flight during compute c
                st[p] = __builtin_nontemporal_load(&zf4[(tb + p*16 + sr)*32 + (c+1)*8 + s8]);
        }
        __syncthreads();                 // buf c&1 ready (lw ready at c==0)

        #pragma unroll
        for (int j = 0; j < 8; ++j) {
            f4 zv[4];
            #pragma unroll
            for (int i = 0; i < 4; ++i)
                zv[i] = *(const f4*)&zb[c&1][(rg*4 + i)*36 + j*4];
            #pragma unroll
            for (int i = 0; i < 4; ++i) {
                sm[i] += zv[i].x + zv[i].y + zv[i].z + zv[i].w;
                sq[i] += zv[i].x*zv[i].x + zv[i].y*zv[i].y + zv[i].z*zv[i].z + zv[i].w*zv[i].w;
            }
            const int cb = c*32 + j*4;
            #pragma unroll
            for (int h = 0; h < 6; ++h) {
                f4 wv = *(const f4*)&lw[(hg*6 + h)*CZ_ + cb];   // wave-uniform broadcast
                #pragma unroll
                for (int i = 0; i < 4; ++i)
                    acc[h][i] += zv[i].x*wv.x + zv[i].y*wv.y + zv[i].z*wv.z + zv[i].w*wv.w;
            }
        }
        __syncthreads();                 // all reads of buf c&1 done
    }

    // ---- epilogue: per-row LN + direct coalesced f4 stores (1KB/wave instr) ----
    float mm[4], rr[4];
    #pragma unroll
    for (int i = 0; i < 4; ++i) {
        mm[i] = sm[i] * (1.f/CZ_);
        rr[i] = rsqrtf(sq[i]*(1.f/CZ_) - mm[i]*mm[i] + EPS_);
    }
    #pragma unroll
    for (int h = 0; h < 6; ++h) {
        const int hh = hg*6 + h;
        const float sw = lsw[hh], bbv = lbb[hh];
        f4 o;
        o.x = rr[0]*(acc[h][0] - mm[0]*sw) + bbv;
        o.y = rr[1]*(acc[h][1] - mm[1]*sw) + bbv;
        o.z = rr[2]*(acc[h][2] - mm[2]*sw) + bbv;
        o.w = rr[3]*(acc[h][3] - mm[3]*sw) + bbv;
        *(f4*)(bias + (size_t)hh*LL_ + tb + rg*4) = o;
    }
}

// ---------------- LayerNorm(s) ----------------
__global__ void sln_kernel(const float* __restrict__ s, const float* __restrict__ w,
                           const float* __restrict__ b, float* __restrict__ sn) {
    int row = blockIdx.x;
    int lane = threadIdx.x;   // 64
    float x[6];
    float sum = 0.f, sum2 = 0.f;
    #pragma unroll
    for (int j = 0; j < 6; ++j) {
        x[j] = s[row*CS_ + lane + j*64];
        sum += x[j]; sum2 += x[j]*x[j];
    }
    #pragma unroll
    for (int off = 32; off; off >>= 1) {
        sum  += __shfl_xor(sum,  off);
        sum2 += __shfl_xor(sum2, off);
    }
    float m = sum * (1.f/CS_);
    float r = rsqrtf(sum2*(1.f/CS_) - m*m + EPS_);
    #pragma unroll
    for (int j = 0; j < 6; ++j) {
        int c = lane + j*64;
        sn[row*CS_ + c] = (x[j]-m)*r*w[c] + b[c];
    }
}

// ---------------- QKVG projections ----------------
__global__ __launch_bounds__(256) void qkvg_kernel(const float* __restrict__ sn,
        const float* __restrict__ wq, const float* __restrict__ wk,
        const float* __restrict__ wv, const float* __restrict__ wg,
        const float* __restrict__ bg,
        float* __restrict__ qb, float* __restrict__ kb,
        float* __restrict__ vb, float* __restrict__ gb) {
    __shared__ float As[16][68];
    __shared__ float Bs[16][68];
    int m0 = blockIdx.x * 64;
    int n0 = blockIdx.y * 64;
    int sel = n0 / 384;
    const float* W = (sel==0) ? wq : (sel==1) ? wk : (sel==2) ? wv : wg;
    float* C       = (sel==0) ? qb : (sel==1) ? kb : (sel==2) ? vb : gb;
    int ncol0 = n0 - sel*384;

    int t  = threadIdx.x;
    int lr = t >> 2;
    int lc = (t & 3) * 4;
    int ty = t >> 4;
    int tx = t & 15;

    float acc[4][4] = {};
    for (int k0 = 0; k0 < CS_; k0 += 16) {
        float4 av = *(const float4*)(sn + (size_t)(m0 + lr)*CS_ + k0 + lc);
        float4 bv = *(const float4*)(W  + (size_t)(ncol0 + lr)*CS_ + k0 + lc);
        As[lc+0][lr] = av.x; As[lc+1][lr] = av.y; As[lc+2][lr] = av.z; As[lc+3][lr] = av.w;
        Bs[lc+0][lr] = bv.x; Bs[lc+1][lr] = bv.y; Bs[lc+2][lr] = bv.z; Bs[lc+3][lr] = bv.w;
        __syncthreads();
        #pragma unroll
        for (int kk = 0; kk < 16; ++kk) {
            float4 a4 = *(const float4*)&As[kk][ty*4];
            float4 b4 = *(const float4*)&Bs[kk][tx*4];
            float a[4] = {a4.x,a4.y,a4.z,a4.w};
            float bb_[4] = {b4.x,b4.y,b4.z,b4.w};
            #pragma unroll
            for (int i = 0; i < 4; ++i)
                #pragma unroll
                for (int j = 0; j < 4; ++j)
                    acc[i][j] += a[i]*bb_[j];
        }
        __syncthreads();
    }
    #pragma unroll
    for (int i = 0; i < 4; ++i) {
        int row = m0 + ty*4 + i;
        #pragma unroll
        for (int j = 0; j < 4; ++j) {
            int col = ncol0 + tx*4 + j;
            float v = acc[i][j];
            if (sel == 0) v *= 0.17677669529663687f;
            if (sel == 3) v = 1.f/(1.f + __expf(-(v + bg[col])));
            C[(size_t)row*CS_ + col] = v;
        }
    }
}

// ---------------- attention: QT=8 rows/block, KT=128 tiles ----------------
#define QT_ 8
__global__ __launch_bounds__(256) void attn_kernel(const float* __restrict__ qb,
        const float* __restrict__ kb, const float* __restrict__ vb,
        const float* __restrict__ gb, const float* __restrict__ bias,
        float* __restrict__ og) {
    __shared__ float Sm[QT_][772];       // 24.7 KB scores
    __shared__ float KVt[CH_][136];      // 17.4 KB K or V tile transposed [c][k]
    int h  = blockIdx.x;
    int q0 = blockIdx.y * QT_;
    int t  = threadIdx.x;

    int tq = t >> 5;    // 0..7 q row
    int tk = t & 31;    // 0..31 k-quad / channel

    float qreg[CH_];
    {
        const float4* qsrc = (const float4*)(qb + (size_t)(q0 + tq)*CS_ + h*CH_);
        #pragma unroll
        for (int i = 0; i < 8; ++i) {
            float4 qv = qsrc[i];
            qreg[i*4+0]=qv.x; qreg[i*4+1]=qv.y; qreg[i*4+2]=qv.z; qreg[i*4+3]=qv.w;
        }
    }

    // ---- phase 1: S = qK^T + bias ----
    for (int kt = 0; kt < L_; kt += 128) {
        #pragma unroll
        for (int r2 = 0; r2 < 4; ++r2) {
            int row = (t >> 3) + 32*r2;        // 0..127
            int c   = (t & 7) * 4;
            f4 kv = *(const f4*)(kb + (size_t)(kt+row)*CS_ + h*CH_ + c);
            KVt[c+0][row]=kv.x; KVt[c+1][row]=kv.y; KVt[c+2][row]=kv.z; KVt[c+3][row]=kv.w;
        }
        __syncthreads();
        f4 sacc = {0,0,0,0};
        #pragma unroll
        for (int c = 0; c < CH_; ++c) {
            f4 kv4 = *(const f4*)&KVt[c][tk*4];
            sacc.x += qreg[c]*kv4.x;
            sacc.y += qreg[c]*kv4.y;
            sacc.z += qreg[c]*kv4.z;
            sacc.w += qreg[c]*kv4.w;
        }
        f4 bv = *(const f4*)(bias + (size_t)h*LL_ + (size_t)(q0+tq)*L_ + kt + tk*4);
        *(f4*)&Sm[tq][kt + tk*4] = sacc + bv;
        __syncthreads();
    }

    // ---- phase 2: softmax (32 lanes per row) ----
    {
        float mx = -1e30f;
        for (int k = tk; k < L_; k += 32) mx = fmaxf(mx, Sm[tq][k]);
        #pragma unroll
        for (int off = 16; off; off >>= 1) mx = fmaxf(mx, __shfl_xor(mx, off));
        float ssum = 0.f;
        for (int k = tk; k < L_; k += 32) {
            float e = __expf(Sm[tq][k] - mx);
            Sm[tq][k] = e;
            ssum += e;
        }
        #pragma unroll
        for (int off = 16; off; off >>= 1) ssum += __shfl_xor(ssum, off);
        float inv = 1.f/ssum;
        for (int k = tk; k < L_; k += 32) Sm[tq][k] *= inv;
        __syncthreads();
    }

    // ---- phase 3: O = P V, gated store (1 channel per thread) ----
    {
        float o = 0.f;
        for (int kt = 0; kt < L_; kt += 128) {
            #pragma unroll
            for (int r2 = 0; r2 < 4; ++r2) {
                int row = (t >> 3) + 32*r2;
                int c   = (t & 7) * 4;
                f4 vv = *(const f4*)(vb + (size_t)(kt+row)*CS_ + h*CH_ + c);
                KVt[c+0][row]=vv.x; KVt[c+1][row]=vv.y; KVt[c+2][row]=vv.z; KVt[c+3][row]=vv.w;
            }
            __syncthreads();
            #pragma unroll
            for (int j4 = 0; j4 < 32; ++j4) {
                f4 pv = *(const f4*)&Sm[tq][kt + j4*4];
                f4 va = *(const f4*)&KVt[tk][j4*4];
                o += pv.x*va.x + pv.y*va.y + pv.z*va.z + pv.w*va.w;
            }
            __syncthreads();
        }
        int row = q0 + tq;
        int c   = h*CH_ + tk;
        og[(size_t)row*CS_ + c] = o * gb[(size_t)row*CS_ + c];
    }
}

// ---------------- out projection: 32x32 tiles, 288 blocks (was 72) ----------------
__global__ __launch_bounds__(256) void outproj_kernel(const float* __restrict__ og,
        const float* __restrict__ wo, const float* __restrict__ bo,
        float* __restrict__ out) {
    __shared__ float As[16][36];
    __shared__ float Bs[16][36];
    int m0 = blockIdx.x * 32;
    int n0 = blockIdx.y * 32;
    int t  = threadIdx.x;
    int lr = t >> 3;            // 0..31
    int lc = (t & 7) * 2;       // 0,2,..,14
    int ty = t >> 4;            // 0..15
    int tx = t & 15;            // 0..15
    float acc[2][2] = {};
    for (int k0 = 0; k0 < CS_; k0 += 16) {
        f2 av = *(const f2*)(og + (size_t)(m0 + lr)*CS_ + k0 + lc);
        f2 bv = *(const f2*)(wo + (size_t)(n0 + lr)*CS_ + k0 + lc);
        As[lc+0][lr] = av.x; As[lc+1][lr] = av.y;
        Bs[lc+0][lr] = bv.x; Bs[lc+1][lr] = bv.y;
        __syncthreads();
        #pragma unroll
        for (int kk = 0; kk < 16; ++kk) {
            f2 a2 = *(const f2*)&As[kk][ty*2];
            f2 b2 = *(const f2*)&Bs[kk][tx*2];
            acc[0][0] += a2.x*b2.x;
            acc[0][1] += a2.x*b2.y;
            acc[1][0] += a2.y*b2.x;
            acc[1][1] += a2.y*b2.y;
        }
        __syncthreads();
    }
    #pragma unroll
    for (int i = 0; i < 2; ++i) {
        int row = m0 + ty*2 + i;
        #pragma unroll
        for (int j = 0; j < 2; ++j) {
            int col = n0 + tx*2 + j;
            out[(size_t)row*CS_ + col] = acc[i][j] + bo[col];
        }
    }
}

extern "C" void kernel_launch(void* const* d_in, const int* in_sizes, int n_in,
                              void* d_out, int out_size, void* d_ws, size_t ws_size,
                              hipStream_t stream) {
    const float* s      = (const float*)d_in[0];
    const float* z      = (const float*)d_in[1];
    const float* ln_s_w = (const float*)d_in[2];
    const float* ln_s_b = (const float*)d_in[3];
    const float* ln_z_w = (const float*)d_in[4];
    const float* ln_z_b = (const float*)d_in[5];
    const float* w_z    = (const float*)d_in[6];
    const float* w_q    = (const float*)d_in[7];
    const float* w_k    = (const float*)d_in[8];
    const float* w_v    = (const float*)d_in[9];
    const float* w_g    = (const float*)d_in[10];
    const float* b_g    = (const float*)d_in[11];
    const float* w_o    = (const float*)d_in[12];
    const float* b_o    = (const float*)d_in[13];
    float* out = (float*)d_out;

    float* ws    = (float*)d_ws;
    float* bias  = ws;
    float* sn    = bias + (size_t)H_*LL_;
    float* qb    = sn + (size_t)L_*CS_;
    float* kb    = qb + (size_t)L_*CS_;
    float* vb    = kb + (size_t)L_*CS_;
    float* gb    = vb + (size_t)L_*CS_;
    float* og    = gb + (size_t)L_*CS_;
    float* ww    = og + (size_t)L_*CS_;
    float* sumww = ww + (size_t)H_*CZ_;
    float* bbuf  = sumww + 16;

    hipLaunchKernelGGL(prep_kernel, dim3(1), dim3(64), 0, stream,
                       ln_z_w, ln_z_b, w_z, ww, sumww, bbuf);
    hipLaunchKernelGGL(bias_kernel, dim3(LL_/256), dim3(128), 0, stream,
                       z, ww, sumww, bbuf, bias);
    hipLaunchKernelGGL(sln_kernel, dim3(L_), dim3(64), 0, stream,
                       s, ln_s_w, ln_s_b, sn);
    hipLaunchKernelGGL(qkvg_kernel, dim3(L_/64, 1536/64), dim3(256), 0, stream,
                       sn, w_q, w_k, w_v, w_g, b_g, qb, kb, vb, gb);
    hipLaunchKernelGGL(attn_kernel, dim3(H_, L_/QT_), dim3(256), 0, stream,
                       qb, kb, vb, gb, bias, og);
    hipLaunchKernelGGL(outproj_kernel, dim3(L_/32, CS_/32), dim3(256), 0, stream,
                       og, w_o, b_o, out);
}

// Round 10
// 204.736 us; speedup vs baseline: 1.1392x; 1.0214x over previous
//
#include <hip/hip_runtime.h>
#include <hip/hip_bf16.h>
#include <cstddef>

#define L_ 768
#define CS_ 384
#define CZ_ 128
#define CH_ 32
#define H_ 12
#define LL_ (L_*L_)
#define EPS_ 1e-5f

typedef float f4 __attribute__((ext_vector_type(4)));
typedef float f2 __attribute__((ext_vector_type(2)));

// ---------------- prep: fold LN(z) affine into w_z (parallel) ----------------
// 16 lanes per head x 8 channels each; shuffle-reduce within the 16-lane group.
__global__ void prep_kernel(const float* __restrict__ lnzw, const float* __restrict__ lnzb,
                            const float* __restrict__ wz,
                            float* __restrict__ ww, float* __restrict__ sumww,
                            float* __restrict__ bb) {
    int t = threadIdx.x;
    int h = t >> 4;
    int c0 = (t & 15) * 8;
    if (h < H_) {
        float sw = 0.f, sb = 0.f;
        #pragma unroll
        for (int c = c0; c < c0 + 8; ++c) {
            float wv = lnzw[c] * wz[h*CZ_ + c];
            ww[h*CZ_ + c] = wv;
            sw += wv;
            sb += lnzb[c] * wz[h*CZ_ + c];
        }
        #pragma unroll
        for (int off = 8; off; off >>= 1) {
            sw += __shfl_xor(sw, off);
            sb += __shfl_xor(sb, off);
        }
        if ((t & 15) == 0) { sumww[h] = sw; bb[h] = sb; }
    }
}

// ---------------- bias: register-tiled, R=4 x Hh=6, conflict-free slot map ----
// R9 had an 8-way bank conflict on z compute reads: rows 4rg+i at stride-36 rows
// give quad (4rg+i+j)%8 with 4rg%8 in {0,4} -> 2 quads. Fix: store row r at LDS
// slot (r>>2)+64*(r&3). Thread rg's rows 4rg+i -> slots rg+64i -> read quad
// (rg+j)%8 = 8 quads x 8 lanes (conflict-free). Stage writes: quad (slot+s8)%8,
// slot%8 spans 2 values x s8 8 values -> 8 quads x 8 lanes (conflict-free).
// Epilogue keeps 1KB-contiguous f4 stores (thread owns 4 consecutive rows).
__global__ __launch_bounds__(128) void bias_kernel(const float* __restrict__ z,
        const float* __restrict__ ww, const float* __restrict__ sumww,
        const float* __restrict__ bb, float* __restrict__ bias) {
    __shared__ float zb[2][256*36];      // 72 KB
    __shared__ float lw[H_*CZ_];         // 6 KB
    __shared__ float lsw[H_];
    __shared__ float lbb[H_];

    const int t  = threadIdx.x;          // 0..127
    const size_t tb = (size_t)blockIdx.x * 256;
    const int sr = t >> 3;               // staging row group 0..15
    const int s8 = t & 7;                // staging 16B slot in line
    const int rg = t & 63;               // compute: row quad 0..63
    const int hg = t >> 6;               // compute: head group (== wave id)

    const f4* zf4 = (const f4*)z;

    f4 st[16];
    #pragma unroll
    for (int p = 0; p < 16; ++p)
        st[p] = __builtin_nontemporal_load(&zf4[(tb + p*16 + sr)*32 + s8]);

    {   // weights -> LDS
        const f4* wwf4 = (const f4*)ww;
        f4* lwf4 = (f4*)lw;
        #pragma unroll
        for (int i = 0; i < 3; ++i) lwf4[i*128 + t] = wwf4[i*128 + t];
        if (t < H_) { lsw[t] = sumww[t]; lbb[t] = bb[t]; }
    }

    float acc[6][4];
    #pragma unroll
    for (int h = 0; h < 6; ++h)
        #pragma unroll
        for (int i = 0; i < 4; ++i) acc[h][i] = 0.f;
    float sm[4] = {0,0,0,0}, sq[4] = {0,0,0,0};

    #pragma unroll 1
    for (int c = 0; c < 4; ++c) {
        #pragma unroll
        for (int p = 0; p < 16; ++p) {
            const int wr = p*16 + sr;                 // row in tile
            const int wsl = (wr >> 2) + 64*(wr & 3);  // bit-rotate slot map
            *(f4*)&zb[c&1][wsl*36 + s8*4] = st[p];
        }
        if (c < 3) {
            #pragma unroll
            for (int p = 0; p < 16; ++p)
                st[p] = __builtin_nontemporal_load(&zf4[(tb + p*16 + sr)*32 + (c+1)*8 + s8]);
        }
        __syncthreads();                 // buf c&1 ready (lw ready at c==0)

        #pragma unroll
        for (int j = 0; j < 8; ++j) {
            f4 zv[4];
            #pragma unroll
            for (int i = 0; i < 4; ++i)
                zv[i] = *(const f4*)&zb[c&1][(rg + 64*i)*36 + j*4];   // slot of row 4rg+i
            #pragma unroll
            for (int i = 0; i < 4; ++i) {
                sm[i] += zv[i].x + zv[i].y + zv[i].z + zv[i].w;
                sq[i] += zv[i].x*zv[i].x + zv[i].y*zv[i].y + zv[i].z*zv[i].z + zv[i].w*zv[i].w;
            }
            const int cb = c*32 + j*4;
            #pragma unroll
            for (int h = 0; h < 6; ++h) {
                f4 wv = *(const f4*)&lw[(hg*6 + h)*CZ_ + cb];   // wave-uniform broadcast
                #pragma unroll
                for (int i = 0; i < 4; ++i)
                    acc[h][i] += zv[i].x*wv.x + zv[i].y*wv.y + zv[i].z*wv.z + zv[i].w*wv.w;
            }
        }
        __syncthreads();                 // all reads of buf c&1 done
    }

    // ---- epilogue: per-row LN + direct coalesced f4 stores ----
    float mm[4], rr[4];
    #pragma unroll
    for (int i = 0; i < 4; ++i) {
        mm[i] = sm[i] * (1.f/CZ_);
        rr[i] = rsqrtf(sq[i]*(1.f/CZ_) - mm[i]*mm[i] + EPS_);
    }
    #pragma unroll
    for (int h = 0; h < 6; ++h) {
        const int hh = hg*6 + h;
        const float sw = lsw[hh], bbv = lbb[hh];
        f4 o;
        o.x = rr[0]*(acc[h][0] - mm[0]*sw) + bbv;
        o.y = rr[1]*(acc[h][1] - mm[1]*sw) + bbv;
        o.z = rr[2]*(acc[h][2] - mm[2]*sw) + bbv;
        o.w = rr[3]*(acc[h][3] - mm[3]*sw) + bbv;
        *(f4*)(bias + (size_t)hh*LL_ + tb + rg*4) = o;
    }
}

// ---------------- LayerNorm(s) ----------------
__global__ void sln_kernel(const float* __restrict__ s, const float* __restrict__ w,
                           const float* __restrict__ b, float* __restrict__ sn) {
    int row = blockIdx.x;
    int lane = threadIdx.x;   // 64
    float x[6];
    float sum = 0.f, sum2 = 0.f;
    #pragma unroll
    for (int j = 0; j < 6; ++j) {
        x[j] = s[row*CS_ + lane + j*64];
        sum += x[j]; sum2 += x[j]*x[j];
    }
    #pragma unroll
    for (int off = 32; off; off >>= 1) {
        sum  += __shfl_xor(sum,  off);
        sum2 += __shfl_xor(sum2, off);
    }
    float m = sum * (1.f/CS_);
    float r = rsqrtf(sum2*(1.f/CS_) - m*m + EPS_);
    #pragma unroll
    for (int j = 0; j < 6; ++j) {
        int c = lane + j*64;
        sn[row*CS_ + c] = (x[j]-m)*r*w[c] + b[c];
    }
}

// ---------------- QKVG projections ----------------
__global__ __launch_bounds__(256) void qkvg_kernel(const float* __restrict__ sn,
        const float* __restrict__ wq, const float* __restrict__ wk,
        const float* __restrict__ wv, const float* __restrict__ wg,
        const float* __restrict__ bg,
        float* __restrict__ qb, float* __restrict__ kb,
        float* __restrict__ vb, float* __restrict__ gb) {
    __shared__ float As[16][68];
    __shared__ float Bs[16][68];
    int m0 = blockIdx.x * 64;
    int n0 = blockIdx.y * 64;
    int sel = n0 / 384;
    const float* W = (sel==0) ? wq : (sel==1) ? wk : (sel==2) ? wv : wg;
    float* C       = (sel==0) ? qb : (sel==1) ? kb : (sel==2) ? vb : gb;
    int ncol0 = n0 - sel*384;

    int t  = threadIdx.x;
    int lr = t >> 2;
    int lc = (t & 3) * 4;
    int ty = t >> 4;
    int tx = t & 15;

    float acc[4][4] = {};
    for (int k0 = 0; k0 < CS_; k0 += 16) {
        float4 av = *(const float4*)(sn + (size_t)(m0 + lr)*CS_ + k0 + lc);
        float4 bv = *(const float4*)(W  + (size_t)(ncol0 + lr)*CS_ + k0 + lc);
        As[lc+0][lr] = av.x; As[lc+1][lr] = av.y; As[lc+2][lr] = av.z; As[lc+3][lr] = av.w;
        Bs[lc+0][lr] = bv.x; Bs[lc+1][lr] = bv.y; Bs[lc+2][lr] = bv.z; Bs[lc+3][lr] = bv.w;
        __syncthreads();
        #pragma unroll
        for (int kk = 0; kk < 16; ++kk) {
            float4 a4 = *(const float4*)&As[kk][ty*4];
            float4 b4 = *(const float4*)&Bs[kk][tx*4];
            float a[4] = {a4.x,a4.y,a4.z,a4.w};
            float bb_[4] = {b4.x,b4.y,b4.z,b4.w};
            #pragma unroll
            for (int i = 0; i < 4; ++i)
                #pragma unroll
                for (int j = 0; j < 4; ++j)
                    acc[i][j] += a[i]*bb_[j];
        }
        __syncthreads();
    }
    #pragma unroll
    for (int i = 0; i < 4; ++i) {
        int row = m0 + ty*4 + i;
        #pragma unroll
        for (int j = 0; j < 4; ++j) {
            int col = ncol0 + tx*4 + j;
            float v = acc[i][j];
            if (sel == 0) v *= 0.17677669529663687f;
            if (sel == 3) v = 1.f/(1.f + __expf(-(v + bg[col])));
            C[(size_t)row*CS_ + col] = v;
        }
    }
}

// ---------------- attention: QT=8 rows/block, KT=128 tiles ----------------
#define QT_ 8
__global__ __launch_bounds__(256) void attn_kernel(const float* __restrict__ qb,
        const float* __restrict__ kb, const float* __restrict__ vb,
        const float* __restrict__ gb, const float* __restrict__ bias,
        float* __restrict__ og) {
    __shared__ float Sm[QT_][772];       // 24.7 KB scores
    __shared__ float KVt[CH_][136];      // 17.4 KB K or V tile transposed [c][k]
    int h  = blockIdx.x;
    int q0 = blockIdx.y * QT_;
    int t  = threadIdx.x;

    int tq = t >> 5;    // 0..7 q row
    int tk = t & 31;    // 0..31 k-quad / channel

    float qreg[CH_];
    {
        const float4* qsrc = (const float4*)(qb + (size_t)(q0 + tq)*CS_ + h*CH_);
        #pragma unroll
        for (int i = 0; i < 8; ++i) {
            float4 qv = qsrc[i];
            qreg[i*4+0]=qv.x; qreg[i*4+1]=qv.y; qreg[i*4+2]=qv.z; qreg[i*4+3]=qv.w;
        }
    }

    // ---- phase 1: S = qK^T + bias ----
    for (int kt = 0; kt < L_; kt += 128) {
        #pragma unroll
        for (int r2 = 0; r2 < 4; ++r2) {
            int row = (t >> 3) + 32*r2;        // 0..127
            int c   = (t & 7) * 4;
            f4 kv = *(const f4*)(kb + (size_t)(kt+row)*CS_ + h*CH_ + c);
            KVt[c+0][row]=kv.x; KVt[c+1][row]=kv.y; KVt[c+2][row]=kv.z; KVt[c+3][row]=kv.w;
        }
        __syncthreads();
        f4 sacc = {0,0,0,0};
        #pragma unroll
        for (int c = 0; c < CH_; ++c) {
            f4 kv4 = *(const f4*)&KVt[c][tk*4];
            sacc.x += qreg[c]*kv4.x;
            sacc.y += qreg[c]*kv4.y;
            sacc.z += qreg[c]*kv4.z;
            sacc.w += qreg[c]*kv4.w;
        }
        f4 bv = *(const f4*)(bias + (size_t)h*LL_ + (size_t)(q0+tq)*L_ + kt + tk*4);
        *(f4*)&Sm[tq][kt + tk*4] = sacc + bv;
        __syncthreads();
    }

    // ---- phase 2: softmax (32 lanes per row) ----
    {
        float mx = -1e30f;
        for (int k = tk; k < L_; k += 32) mx = fmaxf(mx, Sm[tq][k]);
        #pragma unroll
        for (int off = 16; off; off >>= 1) mx = fmaxf(mx, __shfl_xor(mx, off));
        float ssum = 0.f;
        for (int k = tk; k < L_; k += 32) {
            float e = __expf(Sm[tq][k] - mx);
            Sm[tq][k] = e;
            ssum += e;
        }
        #pragma unroll
        for (int off = 16; off; off >>= 1) ssum += __shfl_xor(ssum, off);
        float inv = 1.f/ssum;
        for (int k = tk; k < L_; k += 32) Sm[tq][k] *= inv;
        __syncthreads();
    }

    // ---- phase 3: O = P V, gated store ----
    {
        float o = 0.f;
        for (int kt = 0; kt < L_; kt += 128) {
            #pragma unroll
            for (int r2 = 0; r2 < 4; ++r2) {
                int row = (t >> 3) + 32*r2;
                int c   = (t & 7) * 4;
                f4 vv = *(const f4*)(vb + (size_t)(kt+row)*CS_ + h*CH_ + c);
                KVt[c+0][row]=vv.x; KVt[c+1][row]=vv.y; KVt[c+2][row]=vv.z; KVt[c+3][row]=vv.w;
            }
            __syncthreads();
            #pragma unroll
            for (int j4 = 0; j4 < 32; ++j4) {
                f4 pv = *(const f4*)&Sm[tq][kt + j4*4];
                f4 va = *(const f4*)&KVt[tk][j4*4];
                o += pv.x*va.x + pv.y*va.y + pv.z*va.z + pv.w*va.w;
            }
            __syncthreads();
        }
        int row = q0 + tq;
        int c   = h*CH_ + tk;
        og[(size_t)row*CS_ + c] = o * gb[(size_t)row*CS_ + c];
    }
}

// ---------------- out projection: 32x32 tiles ----------------
__global__ __launch_bounds__(256) void outproj_kernel(const float* __restrict__ og,
        const float* __restrict__ wo, const float* __restrict__ bo,
        float* __restrict__ out) {
    __shared__ float As[16][36];
    __shared__ float Bs[16][36];
    int m0 = blockIdx.x * 32;
    int n0 = blockIdx.y * 32;
    int t  = threadIdx.x;
    int lr = t >> 3;
    int lc = (t & 7) * 2;
    int ty = t >> 4;
    int tx = t & 15;
    float acc[2][2] = {};
    for (int k0 = 0; k0 < CS_; k0 += 16) {
        f2 av = *(const f2*)(og + (size_t)(m0 + lr)*CS_ + k0 + lc);
        f2 bv = *(const f2*)(wo + (size_t)(n0 + lr)*CS_ + k0 + lc);
        As[lc+0][lr] = av.x; As[lc+1][lr] = av.y;
        Bs[lc+0][lr] = bv.x; Bs[lc+1][lr] = bv.y;
        __syncthreads();
        #pragma unroll
        for (int kk = 0; kk < 16; ++kk) {
            f2 a2 = *(const f2*)&As[kk][ty*2];
            f2 b2 = *(const f2*)&Bs[kk][tx*2];
            acc[0][0] += a2.x*b2.x;
            acc[0][1] += a2.x*b2.y;
            acc[1][0] += a2.y*b2.x;
            acc[1][1] += a2.y*b2.y;
        }
        __syncthreads();
    }
    #pragma unroll
    for (int i = 0; i < 2; ++i) {
        int row = m0 + ty*2 + i;
        #pragma unroll
        for (int j = 0; j < 2; ++j) {
            int col = n0 + tx*2 + j;
            out[(size_t)row*CS_ + col] = acc[i][j] + bo[col];
        }
    }
}

extern "C" void kernel_launch(void* const* d_in, const int* in_sizes, int n_in,
                              void* d_out, int out_size, void* d_ws, size_t ws_size,
                              hipStream_t stream) {
    const float* s      = (const float*)d_in[0];
    const float* z      = (const float*)d_in[1];
    const float* ln_s_w = (const float*)d_in[2];
    const float* ln_s_b = (const float*)d_in[3];
    const float* ln_z_w = (const float*)d_in[4];
    const float* ln_z_b = (const float*)d_in[5];
    const float* w_z    = (const float*)d_in[6];
    const float* w_q    = (const float*)d_in[7];
    const float* w_k    = (const float*)d_in[8];
    const float* w_v    = (const float*)d_in[9];
    const float* w_g    = (const float*)d_in[10];
    const float* b_g    = (const float*)d_in[11];
    const float* w_o    = (const float*)d_in[12];
    const float* b_o    = (const float*)d_in[13];
    float* out = (float*)d_out;

    float* ws    = (float*)d_ws;
    float* bias  = ws;
    float* sn    = bias + (size_t)H_*LL_;
    float* qb    = sn + (size_t)L_*CS_;
    float* kb    = qb + (size_t)L_*CS_;
    float* vb    = kb + (size_t)L_*CS_;
    float* gb    = vb + (size_t)L_*CS_;
    float* og    = gb + (size_t)L_*CS_;
    float* ww    = og + (size_t)L_*CS_;
    float* sumww = ww + (size_t)H_*CZ_;
    float* bbuf  = sumww + 16;

    hipLaunchKernelGGL(prep_kernel, dim3(1), dim3(256), 0, stream,
                       ln_z_w, ln_z_b, w_z, ww, sumww, bbuf);
    hipLaunchKernelGGL(bias_kernel, dim3(LL_/256), dim3(128), 0, stream,
                       z, ww, sumww, bbuf, bias);
    hipLaunchKernelGGL(sln_kernel, dim3(L_), dim3(64), 0, stream,
                       s, ln_s_w, ln_s_b, sn);
    hipLaunchKernelGGL(qkvg_kernel, dim3(L_/64, 1536/64), dim3(256), 0, stream,
                       sn, w_q, w_k, w_v, w_g, b_g, qb, kb, vb, gb);
    hipLaunchKernelGGL(attn_kernel, dim3(H_, L_/QT_), dim3(256), 0, stream,
                       qb, kb, vb, gb, bias, og);
    hipLaunchKernelGGL(outproj_kernel, dim3(L_/32, CS_/32), dim3(256), 0, stream,
                       og, w_o, b_o, out);
}